// Round 3
// baseline (739.406 us; speedup 1.0000x reference)
//
#include <hip/hip_runtime.h>
#include <hip/hip_bf16.h>

typedef unsigned short u16;
typedef __attribute__((ext_vector_type(8))) short short8;
typedef __attribute__((ext_vector_type(4))) float f32x4;

#define NN 50000
#define EE 400000
#define GG 256
#define MP 50048   // 391 * 128

static __device__ __forceinline__ __hip_bfloat16 f2b(float x) { return __float2bfloat16(x); }
static __device__ __forceinline__ float b2f(__hip_bfloat16 x) { return __bfloat162float(x); }
static __device__ __forceinline__ void st_out(float* p, float v) { *p = v; }
static __device__ __forceinline__ void st_out(__hip_bfloat16* p, float v) { *p = f2b(v); }

// ---------------- weight packing (f32 inputs -> bf16 GEMM weights) ----------------
// W_pqT [512 x 320]: row c<256 = P weights (Wm1[k][c], k<256); row 256+c = Q weights
// (Wm1[256+k][c] for k<256, Wm1[512+(k-256)][c] for k in [256,272)); rest 0.
__global__ __launch_bounds__(256) void pack_pqT(const float* __restrict__ Wm1, __hip_bfloat16* __restrict__ WpqT) {
    int idx = blockIdx.x * 256 + threadIdx.x;
    if (idx >= 512 * 320) return;
    int c = idx / 320, k = idx - c * 320;
    float v = 0.f;
    if (c < 256) {
        if (k < 256) v = Wm1[k * 256 + c];
    } else {
        int cc = c - 256;
        if (k < 256) v = Wm1[(256 + k) * 256 + cc];
        else if (k < 272) v = Wm1[(512 + (k - 256)) * 256 + cc];
    }
    WpqT[idx] = f2b(v);
}

// W_bigT [256 x 576]: k<272 -> Wn[k][c]; [272,528) filled by pack_bigT_mm; rest 0.
__global__ __launch_bounds__(256) void pack_bigT(const float* __restrict__ Wn, __hip_bfloat16* __restrict__ WbigT) {
    int idx = blockIdx.x * 256 + threadIdx.x;
    if (idx >= 256 * 576) return;
    int c = idx / 576, k = idx - c * 576;
    float v = 0.f;
    if (k < 272) v = Wn[k * 256 + c];
    WbigT[idx] = f2b(v);
}

// W_bigT rows [272,528): (Wm2 @ Wn_s)[r][c]
__global__ __launch_bounds__(256) void pack_bigT_mm(const float* __restrict__ Wm2,
                                                    const float* __restrict__ Wn,
                                                    __hip_bfloat16* __restrict__ WbigT) {
    int r = blockIdx.x, c = threadIdx.x;
    float acc = 0.f;
    for (int j = 0; j < 256; ++j)
        acc += Wm2[r * 256 + j] * Wn[j * 256 + c];
    WbigT[c * 576 + 272 + r] = f2b(acc);
}

// Wc[17][256] = We[:17] @ Wm1[528:784];  bc = be @ Wm1[528:784] + bm1;  crow = bm2 @ Wn_s
__global__ __launch_bounds__(256) void pack_small(const float* __restrict__ We,
                                                  const float* __restrict__ be,
                                                  const float* __restrict__ Wm1,
                                                  const float* __restrict__ bm1,
                                                  const float* __restrict__ bm2,
                                                  const float* __restrict__ Wn,
                                                  float* __restrict__ Wc, float* __restrict__ bc,
                                                  float* __restrict__ crow) {
    int b = blockIdx.x, c = threadIdx.x;
    if (b < 17) {
        float acc = 0.f;
        for (int j = 0; j < 256; ++j)
            acc += We[b * 256 + j] * Wm1[(528 + j) * 256 + c];
        Wc[b * 256 + c] = acc;
    } else if (b == 17) {
        float acc = bm1[c];
        for (int j = 0; j < 256; ++j)
            acc += be[j] * Wm1[(528 + j) * 256 + c];
        bc[c] = acc;
    } else {
        float acc = 0.f;
        for (int j = 0; j < 256; ++j)
            acc += bm2[j] * Wn[j * 256 + c];
        crow[c] = acc;
    }
}

// ---------------- node embedding: XL[n] = [ s(256) | vnorm(16) | 0(304) ] (bf16) ----------------
__global__ __launch_bounds__(256) void embed(const float* __restrict__ node_s,
                                             const float* __restrict__ node_v,
                                             const float* __restrict__ Ws,
                                             const float* __restrict__ bs,
                                             const float* __restrict__ Wv,
                                             const float* __restrict__ bv,
                                             __hip_bfloat16* __restrict__ XL) {
    int n = blockIdx.x, c = threadIdx.x;
    __shared__ float ns[23];
    __shared__ float nv[12];
    if (c < 23) ns[c] = node_s[(size_t)n * 23 + c];
    if (c >= 32 && c < 44) nv[c - 32] = node_v[(size_t)n * 12 + (c - 32)];
    __syncthreads();
    float a = bs[c];
#pragma unroll
    for (int k = 0; k < 23; ++k) a += ns[k] * Ws[k * 256 + c];
    __hip_bfloat16* row = XL + (size_t)n * 576;
    row[c] = f2b(a);
    if (c < 16) {
        float b0 = bv[c];
        float vx = b0, vy = b0, vz = b0;
#pragma unroll
        for (int k = 0; k < 4; ++k) {
            float w = Wv[k * 16 + c];
            vx += nv[k * 3 + 0] * w;
            vy += nv[k * 3 + 1] * w;
            vz += nv[k * 3 + 2] * w;
        }
        row[256 + c] = f2b(sqrtf(vx * vx + vy * vy + vz * vz));
    }
    for (int i = 272 + c; i < 576; i += 256) row[i] = f2b(0.f);
}

// ---------------- CSR build ----------------
__global__ __launch_bounds__(256) void count_edges(const int* __restrict__ ei, int* __restrict__ cnt) {
    int e = blockIdx.x * 256 + threadIdx.x;
    if (e < EE) atomicAdd(&cnt[ei[EE + e]], 1);
}
__global__ __launch_bounds__(256) void count_graphs(const int* __restrict__ batch, int* __restrict__ gcnt) {
    int n = blockIdx.x * 256 + threadIdx.x;
    if (n < NN) atomicAdd(&gcnt[batch[n]], 1);
}
__global__ __launch_bounds__(256) void scan1(const int* __restrict__ cnt, int* __restrict__ rowptr,
                                             int* __restrict__ bsum) {
    int tid = threadIdx.x, i = blockIdx.x * 256 + tid;
    __shared__ int sd[256];
    int v = (i < NN) ? cnt[i] : 0;
    sd[tid] = v;
    __syncthreads();
    for (int off = 1; off < 256; off <<= 1) {
        int t = (tid >= off) ? sd[tid - off] : 0;
        __syncthreads();
        sd[tid] += t;
        __syncthreads();
    }
    if (i < NN) rowptr[i] = sd[tid] - v;
    if (tid == 255) bsum[blockIdx.x] = sd[255];
}
__global__ __launch_bounds__(256) void scan2(int* __restrict__ bsum, const int* __restrict__ gcnt,
                                             int* __restrict__ gstart) {
    int c = threadIdx.x;
    __shared__ int sd[256];
    int v = (c < 196) ? bsum[c] : 0;
    sd[c] = v;
    __syncthreads();
    for (int off = 1; off < 256; off <<= 1) {
        int t = (c >= off) ? sd[c - off] : 0;
        __syncthreads();
        sd[c] += t;
        __syncthreads();
    }
    if (c < 196) bsum[c] = sd[c] - v;
    __syncthreads();
    int g = gcnt[c];
    sd[c] = g;
    __syncthreads();
    for (int off = 1; off < 256; off <<= 1) {
        int t = (c >= off) ? sd[c - off] : 0;
        __syncthreads();
        sd[c] += t;
        __syncthreads();
    }
    gstart[c] = sd[c] - g;
    if (c == 255) gstart[256] = sd[255];
}
__global__ __launch_bounds__(256) void scan3(const int* __restrict__ cnt, const int* __restrict__ bsum,
                                             int* __restrict__ rowptr, int* __restrict__ cursor) {
    int i = blockIdx.x * 256 + threadIdx.x;
    if (i < NN) {
        int v = rowptr[i] + bsum[blockIdx.x];
        rowptr[i] = v;
        cursor[i] = v;
        if (i == NN - 1) rowptr[NN] = v + cnt[i];
    }
}
__global__ __launch_bounds__(256) void fill_csr(const int* __restrict__ ei, int* __restrict__ cursor,
                                                int* __restrict__ eid) {
    int e = blockIdx.x * 256 + threadIdx.x;
    if (e < EE) {
        int d = ei[EE + e];
        int pos = atomicAdd(&cursor[d], 1);
        eid[pos] = e;
    }
}

// ---------------- MFMA GEMM: C[M x Ncols] = A[M x K] * Bt[Ncols x K]^T, bf16 in, OutT out ----------------
// 128x128 tile, BK=64, 4 waves in 2x2; register-staged LDS (m92/m93-verified structure).
template <typename OutT>
__global__ __launch_bounds__(256, 2) void gemm_bt(const u16* __restrict__ A, const u16* __restrict__ Bt,
                                                  OutT* __restrict__ C, int K, int lda, int Ncols) {
    __shared__ __align__(16) u16 At[128 * 64];
    __shared__ __align__(16) u16 Bs[128 * 64];
    int tid = threadIdx.x;
    long m0 = (long)blockIdx.x * 128;
    long n0 = (long)blockIdx.y * 128;
    int wid = tid >> 6, lane = tid & 63;
    int wm = wid >> 1, wn = wid & 1;
    int quad = lane >> 4, l16 = lane & 15;
    f32x4 acc[4][4] = {};
    int r0 = tid >> 3;          // 0..31
    int cc = (tid & 7) * 8;     // 0..56
    const u16* Ab = A + (m0 + r0) * lda + cc;
    const u16* Bb = Bt + (n0 + r0) * K + cc;
    for (int kt = 0; kt < K; kt += 64) {
        short8 ar[4], br[4];
#pragma unroll
        for (int i = 0; i < 4; ++i)
            ar[i] = *(const short8*)(Ab + (long)(i * 32) * lda + kt);
#pragma unroll
        for (int i = 0; i < 4; ++i)
            br[i] = *(const short8*)(Bb + (long)(i * 32) * K + kt);
        __syncthreads();   // previous tile fully consumed before overwrite
#pragma unroll
        for (int i = 0; i < 4; ++i)
            *(short8*)&At[(r0 + i * 32) * 64 + cc] = ar[i];
#pragma unroll
        for (int i = 0; i < 4; ++i)
            *(short8*)&Bs[(r0 + i * 32) * 64 + cc] = br[i];
        __syncthreads();
#pragma unroll
        for (int kk = 0; kk < 64; kk += 32) {
            short8 af[4], bf[4];
#pragma unroll
            for (int mi = 0; mi < 4; ++mi)
                af[mi] = *(const short8*)&At[(wm * 64 + mi * 16 + l16) * 64 + kk + quad * 8];
#pragma unroll
            for (int ni = 0; ni < 4; ++ni)
                bf[ni] = *(const short8*)&Bs[(wn * 64 + ni * 16 + l16) * 64 + kk + quad * 8];
#pragma unroll
            for (int mi = 0; mi < 4; ++mi) {
#pragma unroll
                for (int ni = 0; ni < 4; ++ni)
                    acc[mi][ni] = __builtin_amdgcn_mfma_f32_16x16x32_bf16(af[mi], bf[ni], acc[mi][ni], 0, 0, 0);
            }
        }
    }
#pragma unroll
    for (int mi = 0; mi < 4; ++mi) {
#pragma unroll
        for (int ni = 0; ni < 4; ++ni) {
            long row = m0 + wm * 64 + mi * 16 + quad * 4;
            long col = n0 + wn * 64 + ni * 16 + l16;
#pragma unroll
            for (int r = 0; r < 4; ++r)
                st_out(&C[(row + r) * Ncols + col], acc[mi][ni][r]);
        }
    }
}

// ---------------- per-node edge aggregation ----------------
// hidden_e = relu(P[dst] + Q[src] + edge_s[e]@Wc + bc); meanH written into XL cols [272,528)
__global__ __launch_bounds__(256) void edge_agg(const __hip_bfloat16* __restrict__ PQ,
                                                const float* __restrict__ edge_s,
                                                const int* __restrict__ ei, const int* __restrict__ eid,
                                                const int* __restrict__ rowptr, const float* __restrict__ Wc,
                                                const float* __restrict__ bc, __hip_bfloat16* __restrict__ XL) {
    int n = blockIdx.x, c = threadIdx.x;
    int lane = c & 63;
    float wc[17];
#pragma unroll
    for (int k = 0; k < 17; ++k) wc[k] = Wc[k * 256 + c];
    float p = b2f(PQ[(size_t)n * 512 + c]);
    float bcc = bc[c];
    int start = rowptr[n], end = rowptr[n + 1];
    float acc = 0.f;
    for (int j = start; j < end; ++j) {
        int e = eid[j];
        int src = ei[e];   // same for all threads -> broadcast load
        float esv = (lane < 17) ? edge_s[(size_t)e * 17 + lane] : 0.f;
        float q = b2f(PQ[(size_t)src * 512 + 256 + c]);
        float r = 0.f;
#pragma unroll
        for (int k = 0; k < 17; ++k) r += wc[k] * __shfl(esv, k, 64);
        acc += fmaxf(p + q + r + bcc, 0.f);
    }
    float cd = (float)(end - start);
    XL[(size_t)n * 576 + 272 + c] = f2b(acc / fmaxf(cd, 1.f));
}

// ---------------- LayerNorm + ReLU (in place on f32 h) ----------------
__global__ __launch_bounds__(256) void ln_relu(float* __restrict__ h, const int* __restrict__ cnt,
                                               const float* __restrict__ bn,
                                               const float* __restrict__ crow,
                                               const float* __restrict__ gamma,
                                               const float* __restrict__ beta) {
    int n = blockIdx.x, c = threadIdx.x;
    float x = h[(size_t)n * 256 + c] + bn[c] + (cnt[n] > 0 ? crow[c] : 0.f);
    float s = x, s2 = x * x;
    for (int off = 32; off > 0; off >>= 1) {
        s += __shfl_xor(s, off, 64);
        s2 += __shfl_xor(s2, off, 64);
    }
    __shared__ float ps[4], ps2[4];
    int wid = c >> 6, lane = c & 63;
    if (lane == 0) { ps[wid] = s; ps2[wid] = s2; }
    __syncthreads();
    if (c == 0) {
        ps[0] = ps[0] + ps[1] + ps[2] + ps[3];
        ps2[0] = ps2[0] + ps2[1] + ps2[2] + ps2[3];
    }
    __syncthreads();
    float mu = ps[0] * (1.f / 256.f);
    float var = ps2[0] * (1.f / 256.f) - mu * mu;
    float y = (x - mu) * rsqrtf(var + 1e-5f) * gamma[c] + beta[c];
    h[(size_t)n * 256 + c] = fmaxf(y, 0.f);
}

// ---------------- global mean pool (batch sorted -> contiguous ranges, no atomics) ----------------
__global__ __launch_bounds__(256) void pool(const float* __restrict__ h,
                                            const int* __restrict__ gstart, float* __restrict__ out) {
    int g = blockIdx.x, c = threadIdx.x;
    int s = gstart[g], e = gstart[g + 1];
    float acc = 0.f;
    for (int n = s; n < e; ++n) acc += h[(size_t)n * 256 + c];
    out[g * 256 + c] = acc / fmaxf((float)(e - s), 1.f);
}

extern "C" void kernel_launch(void* const* d_in, const int* in_sizes, int n_in,
                              void* d_out, int out_size, void* d_ws, size_t ws_size,
                              hipStream_t stream) {
    const float* node_s = (const float*)d_in[0];
    const float* node_v = (const float*)d_in[1];
    const float* edge_s = (const float*)d_in[2];
    const int* ei = (const int*)d_in[3];
    const int* batch = (const int*)d_in[4];
    const float* Ws = (const float*)d_in[5];
    const float* bs = (const float*)d_in[6];
    const float* Wv = (const float*)d_in[7];
    const float* bv = (const float*)d_in[8];
    const float* We = (const float*)d_in[9];
    const float* be = (const float*)d_in[10];
    const float* Wm1 = (const float*)d_in[11];
    const float* bm1 = (const float*)d_in[12];
    const float* Wm2 = (const float*)d_in[13];
    const float* bm2 = (const float*)d_in[14];
    const float* Wn = (const float*)d_in[15];
    const float* bn = (const float*)d_in[16];
    const float* gamma = (const float*)d_in[17];
    const float* beta = (const float*)d_in[18];

    char* ws = (char*)d_ws;
    size_t off = 0;
    auto take = [&](size_t n) {
        void* p = ws + off;
        off = (off + n + 255) & ~(size_t)255;
        return p;
    };
    __hip_bfloat16* XL = (__hip_bfloat16*)take((size_t)MP * 576 * 2);
    // PQ (bf16, MP*512*2 B) and h (f32, MP*256*4 B) are the same byte size; h overwrites PQ.
    __hip_bfloat16* PQ = (__hip_bfloat16*)take((size_t)MP * 512 * 2);
    float* h = (float*)PQ;
    __hip_bfloat16* WpqT = (__hip_bfloat16*)take(512 * 320 * 2);
    __hip_bfloat16* WbigT = (__hip_bfloat16*)take(256 * 576 * 2);
    float* Wc = (float*)take(17 * 256 * 4);
    float* bc = (float*)take(256 * 4);
    float* crow = (float*)take(256 * 4);
    int* cnt = (int*)take((NN + GG) * 4);
    int* gcnt = cnt + NN;
    int* rowptr = (int*)take((NN + 1) * 4);
    int* cursor = (int*)take(NN * 4);
    int* eid = (int*)take(EE * 4);
    int* bsum = (int*)take(256 * 4);
    int* gstart = (int*)take(257 * 4);

    hipMemsetAsync(cnt, 0, (NN + GG) * sizeof(int), stream);

    pack_pqT<<<640, 256, 0, stream>>>(Wm1, WpqT);
    pack_bigT<<<576, 256, 0, stream>>>(Wn, WbigT);
    pack_bigT_mm<<<256, 256, 0, stream>>>(Wm2, Wn, WbigT);
    pack_small<<<19, 256, 0, stream>>>(We, be, Wm1, bm1, bm2, Wn, Wc, bc, crow);

    embed<<<NN, 256, 0, stream>>>(node_s, node_v, Ws, bs, Wv, bv, XL);

    count_edges<<<(EE + 255) / 256, 256, 0, stream>>>(ei, cnt);
    count_graphs<<<(NN + 255) / 256, 256, 0, stream>>>(batch, gcnt);
    scan1<<<196, 256, 0, stream>>>(cnt, rowptr, bsum);
    scan2<<<1, 256, 0, stream>>>(bsum, gcnt, gstart);
    scan3<<<196, 256, 0, stream>>>(cnt, bsum, rowptr, cursor);
    fill_csr<<<(EE + 255) / 256, 256, 0, stream>>>(ei, cursor, eid);

    // PQ = XL[:, :320] @ W_pqT^T   (K=320, lda=576, Ncols=512), bf16 out
    gemm_bt<__hip_bfloat16><<<dim3(391, 4), 256, 0, stream>>>((const u16*)XL, (const u16*)WpqT, PQ, 320, 576, 512);

    edge_agg<<<NN, 256, 0, stream>>>(PQ, edge_s, ei, eid, rowptr, Wc, bc, XL);

    // h = XL[:, :576] @ W_bigT^T   (K=576, Ncols=256), f32 out (overwrites PQ bytes)
    gemm_bt<float><<<dim3(391, 2), 256, 0, stream>>>((const u16*)XL, (const u16*)WbigT, h, 576, 576, 256);

    ln_relu<<<NN, 256, 0, stream>>>(h, cnt, bn, crow, gamma, beta);
    pool<<<GG, 256, 0, stream>>>(h, gstart, (float*)d_out);
}

// Round 5
// 532.835 us; speedup vs baseline: 1.3877x; 1.3877x over previous
//
#include <hip/hip_runtime.h>
#include <hip/hip_bf16.h>

typedef unsigned short u16;
typedef __attribute__((ext_vector_type(8))) short short8;
typedef __attribute__((ext_vector_type(4))) short short4v;
typedef __attribute__((ext_vector_type(4))) float f32x4;

#define NN 50000
#define EE 400000
#define GG 256
#define MP 50048   // 391 * 128

static __device__ __forceinline__ __hip_bfloat16 f2b(float x) { return __float2bfloat16(x); }
static __device__ __forceinline__ float b2f(__hip_bfloat16 x) { return __bfloat162float(x); }
static __device__ __forceinline__ float u16tof(u16 v) {
    unsigned int x = ((unsigned int)v) << 16;
    float f;
    __builtin_memcpy(&f, &x, 4);
    return f;
}
static __device__ __forceinline__ u16 ftou16(float x) {
    __hip_bfloat16 h = __float2bfloat16(x);
    u16 b;
    __builtin_memcpy(&b, &h, 2);
    return b;
}
static __device__ __forceinline__ void st_out(float* p, float v) { *p = v; }
static __device__ __forceinline__ void st_out(__hip_bfloat16* p, float v) { *p = f2b(v); }

// ---------------- fused weight packing (one launch; jobs write DISJOINT ranges) ----------------
// blocks [0,640):     W_pqT [512 x 320] (bf16)
// blocks [640,1216):  W_bigT k<272 (Wn) and k>=528 (zero) — SKIPS k in [272,528)!
// blocks [1216,1472): W_bigT rows [272,528) = (Wm2 @ Wn_s)   (sole writer of that range)
// blocks [1472,1491): Wc / bc / crow (f32)
__global__ __launch_bounds__(256) void pack_all(const float* __restrict__ Wm1,
                                                const float* __restrict__ Wn,
                                                const float* __restrict__ Wm2,
                                                const float* __restrict__ We,
                                                const float* __restrict__ be,
                                                const float* __restrict__ bm1,
                                                const float* __restrict__ bm2,
                                                __hip_bfloat16* __restrict__ WpqT,
                                                __hip_bfloat16* __restrict__ WbigT,
                                                float* __restrict__ Wc, float* __restrict__ bc,
                                                float* __restrict__ crow) {
    int blk = blockIdx.x, tid = threadIdx.x;
    if (blk < 640) {
        int idx = blk * 256 + tid;
        int c = idx / 320, k = idx - c * 320;
        float v = 0.f;
        if (c < 256) {
            if (k < 256) v = Wm1[k * 256 + c];
        } else {
            int cc = c - 256;
            if (k < 256) v = Wm1[(256 + k) * 256 + cc];
            else if (k < 272) v = Wm1[(512 + (k - 256)) * 256 + cc];
        }
        WpqT[idx] = f2b(v);
    } else if (blk < 1216) {
        int idx = (blk - 640) * 256 + tid;
        int c = idx / 576, k = idx - c * 576;
        // race-free fusion: [272,528) is owned by the mm job below — do not touch it here
        if (k < 272) WbigT[idx] = f2b(Wn[k * 256 + c]);
        else if (k >= 528) WbigT[idx] = f2b(0.f);
    } else if (blk < 1472) {
        int r = blk - 1216, c = tid;
        float acc = 0.f;
        for (int j = 0; j < 256; ++j)
            acc += Wm2[r * 256 + j] * Wn[j * 256 + c];
        WbigT[c * 576 + 272 + r] = f2b(acc);
    } else {
        int b = blk - 1472, c = tid;
        if (b < 17) {
            float acc = 0.f;
            for (int j = 0; j < 256; ++j)
                acc += We[b * 256 + j] * Wm1[(528 + j) * 256 + c];
            Wc[b * 256 + c] = acc;
        } else if (b == 17) {
            float acc = bm1[c];
            for (int j = 0; j < 256; ++j)
                acc += be[j] * Wm1[(528 + j) * 256 + c];
            bc[c] = acc;
        } else {
            float acc = 0.f;
            for (int j = 0; j < 256; ++j)
                acc += bm2[j] * Wn[j * 256 + c];
            crow[c] = acc;
        }
    }
}

// ---------------- node embedding: XL[n] = [ s(256) | vnorm(16) | meanH(256) | pad(48) ] ----------------
// zero-fills only the K-pad cols actually read by the GEMMs: [272,320) (gemm1) and [528,576) (gemm2)
__global__ __launch_bounds__(256) void embed(const float* __restrict__ node_s,
                                             const float* __restrict__ node_v,
                                             const float* __restrict__ Ws,
                                             const float* __restrict__ bs,
                                             const float* __restrict__ Wv,
                                             const float* __restrict__ bv,
                                             __hip_bfloat16* __restrict__ XL) {
    int n = blockIdx.x, c = threadIdx.x;
    __shared__ float ns[23];
    __shared__ float nv[12];
    if (c < 23) ns[c] = node_s[(size_t)n * 23 + c];
    if (c >= 32 && c < 44) nv[c - 32] = node_v[(size_t)n * 12 + (c - 32)];
    __syncthreads();
    float a = bs[c];
#pragma unroll
    for (int k = 0; k < 23; ++k) a += ns[k] * Ws[k * 256 + c];
    __hip_bfloat16* row = XL + (size_t)n * 576;
    row[c] = f2b(a);
    if (c < 16) {
        float b0 = bv[c];
        float vx = b0, vy = b0, vz = b0;
#pragma unroll
        for (int k = 0; k < 4; ++k) {
            float w = Wv[k * 16 + c];
            vx += nv[k * 3 + 0] * w;
            vy += nv[k * 3 + 1] * w;
            vz += nv[k * 3 + 2] * w;
        }
        row[256 + c] = f2b(sqrtf(vx * vx + vy * vy + vz * vz));
    }
    if (c < 48) {
        row[272 + c] = f2b(0.f);
        row[528 + c] = f2b(0.f);
    }
}

// ---------------- CSR build ----------------
__global__ __launch_bounds__(256) void count_all(const int* __restrict__ ei, const int* __restrict__ batch,
                                                 int* __restrict__ cnt, int* __restrict__ gcnt) {
    int blk = blockIdx.x;
    if (blk < 1563) {
        int e = blk * 256 + threadIdx.x;
        if (e < EE) atomicAdd(&cnt[ei[EE + e]], 1);
    } else {
        int n = (blk - 1563) * 256 + threadIdx.x;
        if (n < NN) atomicAdd(&gcnt[batch[n]], 1);
    }
}
__global__ __launch_bounds__(256) void scan1(const int* __restrict__ cnt, int* __restrict__ rowptr,
                                             int* __restrict__ bsum) {
    int tid = threadIdx.x, i = blockIdx.x * 256 + tid;
    __shared__ int sd[256];
    int v = (i < NN) ? cnt[i] : 0;
    sd[tid] = v;
    __syncthreads();
    for (int off = 1; off < 256; off <<= 1) {
        int t = (tid >= off) ? sd[tid - off] : 0;
        __syncthreads();
        sd[tid] += t;
        __syncthreads();
    }
    if (i < NN) rowptr[i] = sd[tid] - v;
    if (tid == 255) bsum[blockIdx.x] = sd[255];
}
__global__ __launch_bounds__(256) void scan2(int* __restrict__ bsum, const int* __restrict__ gcnt,
                                             int* __restrict__ gstart) {
    int c = threadIdx.x;
    __shared__ int sd[256];
    int v = (c < 196) ? bsum[c] : 0;
    sd[c] = v;
    __syncthreads();
    for (int off = 1; off < 256; off <<= 1) {
        int t = (c >= off) ? sd[c - off] : 0;
        __syncthreads();
        sd[c] += t;
        __syncthreads();
    }
    if (c < 196) bsum[c] = sd[c] - v;
    __syncthreads();
    int g = gcnt[c];
    sd[c] = g;
    __syncthreads();
    for (int off = 1; off < 256; off <<= 1) {
        int t = (c >= off) ? sd[c - off] : 0;
        __syncthreads();
        sd[c] += t;
        __syncthreads();
    }
    gstart[c] = sd[c] - g;
    if (c == 255) gstart[256] = sd[255];
}
__global__ __launch_bounds__(256) void scan3(const int* __restrict__ cnt, const int* __restrict__ bsum,
                                             int* __restrict__ rowptr, int* __restrict__ cursor) {
    int i = blockIdx.x * 256 + threadIdx.x;
    if (i < NN) {
        int v = rowptr[i] + bsum[blockIdx.x];
        rowptr[i] = v;
        cursor[i] = v;
        if (i == NN - 1) rowptr[NN] = v + cnt[i];
    }
}
__global__ __launch_bounds__(256) void fill_csr(const int* __restrict__ ei, int* __restrict__ cursor,
                                                int* __restrict__ eid) {
    int e = blockIdx.x * 256 + threadIdx.x;
    if (e < EE) {
        int d = ei[EE + e];
        int pos = atomicAdd(&cursor[d], 1);
        eid[pos] = e;
    }
}

// ---------------- MFMA GEMM: C[M x Ncols] = A[M x K] * Bt[Ncols x K]^T, bf16 in, OutT out ----------------
// 128x128 tile, BK=64, 4 waves in 2x2; register-staged LDS (verified passing structure).
template <typename OutT>
__global__ __launch_bounds__(256, 2) void gemm_bt(const u16* __restrict__ A, const u16* __restrict__ Bt,
                                                  OutT* __restrict__ C, int K, int lda, int Ncols) {
    __shared__ __align__(16) u16 At[128 * 64];
    __shared__ __align__(16) u16 Bs[128 * 64];
    int tid = threadIdx.x;
    long m0 = (long)blockIdx.x * 128;
    long n0 = (long)blockIdx.y * 128;
    int wid = tid >> 6, lane = tid & 63;
    int wm = wid >> 1, wn = wid & 1;
    int quad = lane >> 4, l16 = lane & 15;
    f32x4 acc[4][4] = {};
    int r0 = tid >> 3;          // 0..31
    int cc = (tid & 7) * 8;     // 0..56
    const u16* Ab = A + (m0 + r0) * lda + cc;
    const u16* Bb = Bt + (n0 + r0) * K + cc;
    for (int kt = 0; kt < K; kt += 64) {
        short8 ar[4], br[4];
#pragma unroll
        for (int i = 0; i < 4; ++i)
            ar[i] = *(const short8*)(Ab + (long)(i * 32) * lda + kt);
#pragma unroll
        for (int i = 0; i < 4; ++i)
            br[i] = *(const short8*)(Bb + (long)(i * 32) * K + kt);
        __syncthreads();   // previous tile fully consumed before overwrite
#pragma unroll
        for (int i = 0; i < 4; ++i)
            *(short8*)&At[(r0 + i * 32) * 64 + cc] = ar[i];
#pragma unroll
        for (int i = 0; i < 4; ++i)
            *(short8*)&Bs[(r0 + i * 32) * 64 + cc] = br[i];
        __syncthreads();
#pragma unroll
        for (int kk = 0; kk < 64; kk += 32) {
            short8 af[4], bf[4];
#pragma unroll
            for (int mi = 0; mi < 4; ++mi)
                af[mi] = *(const short8*)&At[(wm * 64 + mi * 16 + l16) * 64 + kk + quad * 8];
#pragma unroll
            for (int ni = 0; ni < 4; ++ni)
                bf[ni] = *(const short8*)&Bs[(wn * 64 + ni * 16 + l16) * 64 + kk + quad * 8];
#pragma unroll
            for (int mi = 0; mi < 4; ++mi) {
#pragma unroll
                for (int ni = 0; ni < 4; ++ni)
                    acc[mi][ni] = __builtin_amdgcn_mfma_f32_16x16x32_bf16(af[mi], bf[ni], acc[mi][ni], 0, 0, 0);
            }
        }
    }
#pragma unroll
    for (int mi = 0; mi < 4; ++mi) {
#pragma unroll
        for (int ni = 0; ni < 4; ++ni) {
            long row = m0 + wm * 64 + mi * 16 + quad * 4;
            long col = n0 + wn * 64 + ni * 16 + l16;
#pragma unroll
            for (int r = 0; r < 4; ++r)
                st_out(&C[(row + r) * Ncols + col], acc[mi][ni][r]);
        }
    }
}

// ---------------- per-node edge aggregation: ONE WAVE PER NODE, 4 channels/lane ----------------
// hidden_e = relu(P[dst] + Q[src] + edge_s[e]@Wc + bc); meanH -> XL cols [272,528).
// Staging: one shot of (eid, ei) loads for up to 64 edges, broadcast via shfl.
// Depth-2 software pipeline on the Q-row (8B/lane) and edge_s loads.
__global__ __launch_bounds__(256) void edge_agg(const u16* __restrict__ PQ,
                                                const float* __restrict__ edge_s,
                                                const int* __restrict__ ei, const int* __restrict__ eid,
                                                const int* __restrict__ rowptr, const float* __restrict__ Wc,
                                                const float* __restrict__ bc, __hip_bfloat16* __restrict__ XL) {
    int w = threadIdx.x >> 6, lane = threadIdx.x & 63;
    int n = blockIdx.x * 4 + w;
    if (n >= NN) return;
    int start = rowptr[n], deg = rowptr[n + 1] - start;
    f32x4 wc4[17];
#pragma unroll
    for (int k = 0; k < 17; ++k) wc4[k] = *(const f32x4*)&Wc[k * 256 + lane * 4];
    f32x4 bc4 = *(const f32x4*)&bc[lane * 4];
    short4v p4 = *(const short4v*)&PQ[(size_t)n * 512 + lane * 4];
    f32x4 p;
#pragma unroll
    for (int i = 0; i < 4; ++i) p[i] = u16tof((u16)p4[i]);
    f32x4 acc = {0.f, 0.f, 0.f, 0.f};
    for (int base = 0; base < deg; base += 64) {
        int m = deg - base;
        if (m > 64) m = 64;
        int ee = 0, ss = 0;
        if (lane < m) {
            ee = eid[start + base + lane];
            ss = ei[ee];
        }
        // prologue: prefetch edge 0
        int e0 = __shfl(ee, 0), s0 = __shfl(ss, 0);
        short4v q0 = *(const short4v*)&PQ[(size_t)s0 * 512 + 256 + lane * 4];
        float es0 = (lane < 17) ? edge_s[(size_t)e0 * 17 + lane] : 0.f;
        for (int jj = 0; jj < m; ++jj) {
            short4v q1 = q0;
            float es1 = es0;
            if (jj + 1 < m) {   // wave-uniform
                int e1 = __shfl(ee, jj + 1), s1 = __shfl(ss, jj + 1);
                q1 = *(const short4v*)&PQ[(size_t)s1 * 512 + 256 + lane * 4];
                es1 = (lane < 17) ? edge_s[(size_t)e1 * 17 + lane] : 0.f;
            }
            f32x4 r = bc4;
#pragma unroll
            for (int k = 0; k < 17; ++k) {
                float ev = __shfl(es0, k);
                r += wc4[k] * ev;
            }
#pragma unroll
            for (int i = 0; i < 4; ++i)
                acc[i] += fmaxf(p[i] + u16tof((u16)q0[i]) + r[i], 0.f);
            q0 = q1;
            es0 = es1;
        }
    }
    float inv = 1.f / fmaxf((float)deg, 1.f);
    short4v ov;
#pragma unroll
    for (int i = 0; i < 4; ++i) ov[i] = (short)ftou16(acc[i] * inv);
    *(short4v*)&XL[(size_t)n * 576 + 272 + lane * 4] = ov;
}

// ---------------- LayerNorm + ReLU (in place on f32 h) ----------------
__global__ __launch_bounds__(256) void ln_relu(float* __restrict__ h, const int* __restrict__ cnt,
                                               const float* __restrict__ bn,
                                               const float* __restrict__ crow,
                                               const float* __restrict__ gamma,
                                               const float* __restrict__ beta) {
    int n = blockIdx.x, c = threadIdx.x;
    float x = h[(size_t)n * 256 + c] + bn[c] + (cnt[n] > 0 ? crow[c] : 0.f);
    float s = x, s2 = x * x;
    for (int off = 32; off > 0; off >>= 1) {
        s += __shfl_xor(s, off, 64);
        s2 += __shfl_xor(s2, off, 64);
    }
    __shared__ float ps[4], ps2[4];
    int wid = c >> 6, lane = c & 63;
    if (lane == 0) { ps[wid] = s; ps2[wid] = s2; }
    __syncthreads();
    if (c == 0) {
        ps[0] = ps[0] + ps[1] + ps[2] + ps[3];
        ps2[0] = ps2[0] + ps2[1] + ps2[2] + ps2[3];
    }
    __syncthreads();
    float mu = ps[0] * (1.f / 256.f);
    float var = ps2[0] * (1.f / 256.f) - mu * mu;
    float y = (x - mu) * rsqrtf(var + 1e-5f) * gamma[c] + beta[c];
    h[(size_t)n * 256 + c] = fmaxf(y, 0.f);
}

// ---------------- global mean pool (contiguous ranges, unroll x4 for load ILP) ----------------
__global__ __launch_bounds__(256) void pool(const float* __restrict__ h,
                                            const int* __restrict__ gstart, float* __restrict__ out) {
    int g = blockIdx.x, c = threadIdx.x;
    int s = gstart[g], e = gstart[g + 1];
    float a0 = 0.f, a1 = 0.f, a2 = 0.f, a3 = 0.f;
    int n = s;
    for (; n + 3 < e; n += 4) {
        a0 += h[(size_t)n * 256 + c];
        a1 += h[(size_t)(n + 1) * 256 + c];
        a2 += h[(size_t)(n + 2) * 256 + c];
        a3 += h[(size_t)(n + 3) * 256 + c];
    }
    for (; n < e; ++n) a0 += h[(size_t)n * 256 + c];
    out[g * 256 + c] = (a0 + a1 + a2 + a3) / fmaxf((float)(e - s), 1.f);
}

extern "C" void kernel_launch(void* const* d_in, const int* in_sizes, int n_in,
                              void* d_out, int out_size, void* d_ws, size_t ws_size,
                              hipStream_t stream) {
    const float* node_s = (const float*)d_in[0];
    const float* node_v = (const float*)d_in[1];
    const float* edge_s = (const float*)d_in[2];
    const int* ei = (const int*)d_in[3];
    const int* batch = (const int*)d_in[4];
    const float* Ws = (const float*)d_in[5];
    const float* bs = (const float*)d_in[6];
    const float* Wv = (const float*)d_in[7];
    const float* bv = (const float*)d_in[8];
    const float* We = (const float*)d_in[9];
    const float* be = (const float*)d_in[10];
    const float* Wm1 = (const float*)d_in[11];
    const float* bm1 = (const float*)d_in[12];
    const float* Wm2 = (const float*)d_in[13];
    const float* bm2 = (const float*)d_in[14];
    const float* Wn = (const float*)d_in[15];
    const float* bn = (const float*)d_in[16];
    const float* gamma = (const float*)d_in[17];
    const float* beta = (const float*)d_in[18];

    char* ws = (char*)d_ws;
    size_t off = 0;
    auto take = [&](size_t n) {
        void* p = ws + off;
        off = (off + n + 255) & ~(size_t)255;
        return p;
    };
    __hip_bfloat16* XL = (__hip_bfloat16*)take((size_t)MP * 576 * 2);
    // PQ (bf16, MP*512*2 B) and h (f32, MP*256*4 B) are the same byte size; h overwrites PQ.
    __hip_bfloat16* PQ = (__hip_bfloat16*)take((size_t)MP * 512 * 2);
    float* h = (float*)PQ;
    __hip_bfloat16* WpqT = (__hip_bfloat16*)take(512 * 320 * 2);
    __hip_bfloat16* WbigT = (__hip_bfloat16*)take(256 * 576 * 2);
    float* Wc = (float*)take(17 * 256 * 4);
    float* bc = (float*)take(256 * 4);
    float* crow = (float*)take(256 * 4);
    int* cnt = (int*)take((NN + GG) * 4);
    int* gcnt = cnt + NN;
    int* rowptr = (int*)take((NN + 1) * 4);
    int* cursor = (int*)take(NN * 4);
    int* eid = (int*)take(EE * 4);
    int* bsum = (int*)take(256 * 4);
    int* gstart = (int*)take(257 * 4);

    hipMemsetAsync(cnt, 0, (NN + GG) * sizeof(int), stream);

    pack_all<<<1491, 256, 0, stream>>>(Wm1, Wn, Wm2, We, be, bm1, bm2, WpqT, WbigT, Wc, bc, crow);

    embed<<<NN, 256, 0, stream>>>(node_s, node_v, Ws, bs, Wv, bv, XL);

    count_all<<<1759, 256, 0, stream>>>(ei, batch, cnt, gcnt);
    scan1<<<196, 256, 0, stream>>>(cnt, rowptr, bsum);
    scan2<<<1, 256, 0, stream>>>(bsum, gcnt, gstart);
    scan3<<<196, 256, 0, stream>>>(cnt, bsum, rowptr, cursor);
    fill_csr<<<(EE + 255) / 256, 256, 0, stream>>>(ei, cursor, eid);

    // PQ = XL[:, :320] @ W_pqT^T   (K=320, lda=576, Ncols=512), bf16 out
    gemm_bt<__hip_bfloat16><<<dim3(391, 4), 256, 0, stream>>>((const u16*)XL, (const u16*)WpqT, PQ, 320, 576, 512);

    edge_agg<<<12500, 256, 0, stream>>>((const u16*)PQ, edge_s, ei, eid, rowptr, Wc, bc, XL);

    // h = XL[:, :576] @ W_bigT^T   (K=576, Ncols=256), f32 out (overwrites PQ bytes)
    gemm_bt<float><<<dim3(391, 2), 256, 0, stream>>>((const u16*)XL, (const u16*)WbigT, h, 576, 576, 256);

    ln_relu<<<NN, 256, 0, stream>>>(h, cnt, bn, crow, gamma, beta);
    pool<<<GG, 256, 0, stream>>>(h, gstart, (float*)d_out);
}